// Round 16
// baseline (379.843 us; speedup 1.0000x reference)
//
#include <hip/hip_runtime.h>
#include <hip/hip_bf16.h>
#include <cstdio>
#include <cstdint>

#define T_TOK   8192
#define H_DIM   1024
#define I_DIM   2048
#define E_NUM   8
#define BM      128
#define BK2     32
#define PADMAX  17408         // T*K + E*BM
#define MAX_TILES 136         // T*K/BM + E
#define HB      32            // histogram/scatter blocks
#define PAIRS_PER_HB (T_TOK*2/HB)   // 512

#define OUT_FRAC  8388608
#define OUT_AVG   8388616
#define OUT_LOG   8388624
#define OUT_PROB  8454160

typedef short short8v __attribute__((ext_vector_type(8)));
typedef float f32x4   __attribute__((ext_vector_type(4)));
typedef unsigned int u32x4 __attribute__((ext_vector_type(4)));

#define AS1 __attribute__((address_space(1)))
#define AS3 __attribute__((address_space(3)))
__device__ __forceinline__ void gload16(const void* g, void* l){
  __builtin_amdgcn_global_load_lds((const AS1 void*)g, (AS3 void*)l, 16, 0, 0);
}

#define WAITV6_BAR asm volatile("s_waitcnt vmcnt(6)\n\ts_barrier" ::: "memory")
#define WAITV4_BAR asm volatile("s_waitcnt vmcnt(4)\n\ts_barrier" ::: "memory")
#define WAITV0_BAR asm volatile("s_waitcnt vmcnt(0)\n\ts_barrier" ::: "memory")
#define SCHED0 __builtin_amdgcn_sched_barrier(0)

__device__ __forceinline__ uint32_t f2bf(float f){
  union { float f; uint32_t u; } v; v.f = f;
  return (v.u + 0x7FFFu + ((v.u >> 16) & 1u)) >> 16;   // RNE
}
__device__ __forceinline__ uint32_t pack2(float a, float b){
  return f2bf(a) | (f2bf(b) << 16);
}
__device__ __forceinline__ float bflo(uint32_t u){ union{uint32_t u;float f;}v; v.u = u<<16; return v.f; }
__device__ __forceinline__ float bfhi(uint32_t u){ union{uint32_t u;float f;}v; v.u = u & 0xFFFF0000u; return v.f; }

// ---------------- fused fp32 -> bf16 bulk convert (x, gw, uw, dw) ----------------
#define NXB  (T_TOK*H_DIM/2048)          // 4096
#define NWB  (E_NUM*I_DIM*H_DIM/2048)    // 8192
__global__ __launch_bounds__(256) void convert4_kernel(
    const float* __restrict__ x,  const float* __restrict__ gw,
    const float* __restrict__ uw, const float* __restrict__ dw,
    ushort* __restrict__ xb, ushort* __restrict__ gwb,
    ushort* __restrict__ uwb, ushort* __restrict__ dwb){
  const int b = blockIdx.x;
  const float* src; ushort* dst; size_t base;
  if (b < NXB)            { src = x;  dst = xb;  base = (size_t)b * 2048; }
  else if (b < NXB+NWB)   { src = gw; dst = gwb; base = (size_t)(b-NXB) * 2048; }
  else if (b < NXB+2*NWB) { src = uw; dst = uwb; base = (size_t)(b-NXB-NWB) * 2048; }
  else                    { src = dw; dst = dwb; base = (size_t)(b-NXB-2*NWB) * 2048; }
  size_t i = base + (size_t)threadIdx.x * 8;
  f32x4 f0 = *(const f32x4*)(src + i);
  f32x4 f1 = *(const f32x4*)(src + i + 4);
  u32x4 o;
  o.x = pack2(f0.x, f0.y); o.y = pack2(f0.z, f0.w);
  o.z = pack2(f1.x, f1.y); o.w = pack2(f1.z, f1.w);
  *(u32x4*)(dst + i) = o;
}

// ---------------- router: logits/softmax/top2; per-block avg partials; NO global atomics ----------------
__global__ __launch_bounds__(256) void router_kernel(const float* __restrict__ x,
    const float* __restrict__ rw, float* __restrict__ out,
    int* __restrict__ pe, float* __restrict__ pw, float* __restrict__ avg_part){
  __shared__ float s_rw[E_NUM * H_DIM];
  __shared__ float s_avg[E_NUM];
  const int tid = threadIdx.x;
  for (int i = tid; i < E_NUM*H_DIM/4; i += 256)
    ((float4*)s_rw)[i] = ((const float4*)rw)[i];
  if (tid < E_NUM) s_avg[tid] = 0.f;
  __syncthreads();
  const int lane = tid & 63;
  const int t = blockIdx.x * 4 + (tid >> 6);
  float acc[E_NUM];
  #pragma unroll
  for (int e=0;e<E_NUM;e++) acc[e] = 0.f;
  const float* xr = x + (size_t)t * H_DIM;
  for (int c=0;c<H_DIM/64;c++){
    float xv = xr[c*64 + lane];
    #pragma unroll
    for (int e=0;e<E_NUM;e++) acc[e] += xv * s_rw[e*H_DIM + c*64 + lane];
  }
  #pragma unroll
  for (int e=0;e<E_NUM;e++){
    #pragma unroll
    for (int off=32; off; off>>=1) acc[e] += __shfl_xor(acc[e], off);
  }
  if (lane == 0){
    float m = acc[0];
    #pragma unroll
    for (int e=1;e<E_NUM;e++) m = fmaxf(m, acc[e]);
    float p[E_NUM]; float s = 0.f;
    #pragma unroll
    for (int e=0;e<E_NUM;e++){ p[e] = __expf(acc[e]-m); s += p[e]; }
    float inv = 1.f/s;
    #pragma unroll
    for (int e=0;e<E_NUM;e++) p[e] *= inv;
    float* lg = out + OUT_LOG  + (size_t)t*E_NUM;
    float* pr = out + OUT_PROB + (size_t)t*E_NUM;
    #pragma unroll
    for (int e=0;e<E_NUM;e++){ lg[e] = acc[e]; pr[e] = p[e]; }
    #pragma unroll
    for (int e=0;e<E_NUM;e++) atomicAdd(&s_avg[e], p[e]);   // LDS atomic (cheap)
    int e1 = 0; float p1 = p[0];
    #pragma unroll
    for (int e=1;e<E_NUM;e++) if (p[e] > p1){ p1 = p[e]; e1 = e; }
    int e2 = -1; float p2 = -1.f;
    #pragma unroll
    for (int e=0;e<E_NUM;e++) if (e != e1 && p[e] > p2){ p2 = p[e]; e2 = e; }
    float rs = 1.f/(p1+p2);
    pe[2*t]   = e1; pw[2*t]   = p1*rs;
    pe[2*t+1] = e2; pw[2*t+1] = p2*rs;
  }
  __syncthreads();
  if (tid < E_NUM) avg_part[blockIdx.x*E_NUM + tid] = s_avg[tid];
}

// ---------------- per-block expert histogram (LDS atomics only) ----------------
__global__ __launch_bounds__(256) void hist_kernel(const int* __restrict__ pe,
                                                   int* __restrict__ block_hist){
  __shared__ int h[E_NUM];
  if (threadIdx.x < E_NUM) h[threadIdx.x] = 0;
  __syncthreads();
  const int base = blockIdx.x * PAIRS_PER_HB;
  for (int i = threadIdx.x; i < PAIRS_PER_HB; i += 256)
    atomicAdd(&h[pe[base + i]], 1);
  __syncthreads();
  if (threadIdx.x < E_NUM) block_hist[blockIdx.x*E_NUM + threadIdx.x] = h[threadIdx.x];
}

// ---------------- offsets: counts/frac/avg + tile table + per-block bases + zero pads ----------------
__global__ __launch_bounds__(256) void offsets_kernel(const int* __restrict__ block_hist,
    const float* __restrict__ avg_part, int* __restrict__ block_base,
    int* __restrict__ tile_e, int* __restrict__ tile_r, int* __restrict__ hdr,
    int* __restrict__ s_tok, float* __restrict__ s_wt, float* __restrict__ out){
  __shared__ int counts[E_NUM];
  __shared__ float ap[256];
  const int tid = threadIdx.x;
  {
    const int e = tid & 7, chunk = tid >> 3;
    float s = 0.f;
    #pragma unroll 8
    for (int i = 0; i < 64; ++i)
      s += avg_part[(chunk*64 + i)*E_NUM + e];
    ap[tid] = s;
  }
  if (tid < E_NUM){
    int c = 0;
    #pragma unroll
    for (int b = 0; b < HB; ++b) c += block_hist[b*E_NUM + tid];
    counts[tid] = c;
  }
  __syncthreads();
  if (tid < E_NUM){
    float tot = 0.f;
    #pragma unroll
    for (int c = 0; c < 32; ++c) tot += ap[c*8 + tid];
    out[OUT_AVG  + tid] = tot * (1.f/8192.f);
    out[OUT_FRAC + tid] = (float)counts[tid] * (1.f/16384.f);
  }
  if (tid == 0){
    int base = 0, tt = 0;
    for (int e=0;e<E_NUM;e++){
      int run = base;
      for (int b=0;b<HB;b++){
        block_base[b*E_NUM + e] = run;
        run += block_hist[b*E_NUM + e];
      }
      int nt = (counts[e] + BM - 1) / BM;
      for (int i=0;i<nt;i++){ tile_e[tt] = e; tile_r[tt] = base + i*BM; tt++; }
      base += nt * BM;
    }
    hdr[0] = tt; hdr[1] = base;
  }
  for (int i = tid; i < PADMAX; i += blockDim.x){
    s_tok[i] = 0; s_wt[i] = 0.f;
  }
}

// ---------------- scatter: local rank via LDS atomics + precomputed block base ----------------
__global__ __launch_bounds__(256) void scatter_kernel(const int* __restrict__ pe,
    const float* __restrict__ pw, const int* __restrict__ block_base,
    int* __restrict__ s_tok, float* __restrict__ s_wt, int* __restrict__ slot_idx){
  __shared__ int h[E_NUM];
  if (threadIdx.x < E_NUM) h[threadIdx.x] = 0;
  __syncthreads();
  const int base = blockIdx.x * PAIRS_PER_HB;
  for (int i = threadIdx.x; i < PAIRS_PER_HB; i += 256){
    const int pi = base + i;
    const int e = pe[pi];
    const int r = atomicAdd(&h[e], 1);
    const int idx = block_base[blockIdx.x*E_NUM + e] + r;
    s_tok[idx] = pi >> 1;
    s_wt[idx]  = pw[pi];
    slot_idx[pi] = idx;
  }
}

// ---------------- gate+up GEMM: 128x128, 4 waves, 3-buf depth-2, ONE barrier/K-step ----------------
__global__ __launch_bounds__(256, 2) void gateup_kernel(
    const ushort* __restrict__ xb, const ushort* __restrict__ gwb,
    const ushort* __restrict__ uwb, const int* __restrict__ s_tok,
    const int* __restrict__ tile_e, const int* __restrict__ tile_r,
    const int* __restrict__ hdr, ushort* __restrict__ h1)
{
  const int tile = blockIdx.y;
  if (tile >= hdr[0]) return;
  __shared__ short sA[3][BM*BK2];
  __shared__ short sG[3][BM*BK2];
  __shared__ short sU[3][BM*BK2];     // 72 KB -> 2 blocks/CU (reg-limited anyway)
  const int e = tile_e[tile];
  const int row0 = tile_r[tile];
  const int n0 = blockIdx.x * 128;
  const int tid = threadIdx.x, lane = tid & 63, wid = tid >> 6;

  const int srow = tid >> 2;
  const int scg  = ((tid & 3) ^ ((tid >> 3) & 3)) * 8;
  const int d0 = tid * 8, d1 = tid * 8 + 2048;
  const ushort* gA0 = xb  + (size_t)s_tok[row0 + srow]      * H_DIM + scg;
  const ushort* gA1 = xb  + (size_t)s_tok[row0 + srow + 64] * H_DIM + scg;
  const ushort* gG0 = gwb + ((size_t)e*I_DIM + n0 + srow)      * H_DIM + scg;
  const ushort* gG1 = gwb + ((size_t)e*I_DIM + n0 + srow + 64) * H_DIM + scg;
  const ushort* gU0 = uwb + ((size_t)e*I_DIM + n0 + srow)      * H_DIM + scg;
  const ushort* gU1 = uwb + ((size_t)e*I_DIM + n0 + srow + 64) * H_DIM + scg;

  const int wm = (wid >> 1) * 64, wn = (wid & 1) * 64;
  const int lr = lane & 15, q = lane >> 4;
  const int swc = (q ^ ((lr >> 1) & 3)) * 8;

  f32x4 accG[4][4] = {};
  f32x4 accU[4][4] = {};

  gload16(gA0,       &sA[0][d0]); gload16(gA1,       &sA[0][d1]);
  gload16(gG0,       &sG[0][d0]); gload16(gG1,       &sG[0][d1]);
  gload16(gU0,       &sU[0][d0]); gload16(gU1,       &sU[0][d1]);
  gload16(gA0 + BK2, &sA[1][d0]); gload16(gA1 + BK2, &sA[1][d1]);
  gload16(gG0 + BK2, &sG[1][d0]); gload16(gG1 + BK2, &sG[1][d1]);
  gload16(gU0 + BK2, &sU[1][d0]); gload16(gU1 + BK2, &sU[1][d1]);
  WAITV6_BAR;

  const int NK = H_DIM / BK2;   // 32
  int b0 = 0, b1 = 1, b2 = 2;
  for (int kt = 0; kt < NK; ++kt){
    short8v a_[4], bg_[4], bu_[4];
    // frag reads (A,G) + stage kt+2 (all 6), then MFMA accG
    #pragma unroll
    for (int mi=0;mi<4;mi++)
      a_[mi] = *(const short8v*)&sA[b0][(wm + mi*16 + lr)*BK2 + swc];
    #pragma unroll
    for (int ni=0;ni<4;ni++)
      bg_[ni] = *(const short8v*)&sG[b0][(wn + ni*16 + lr)*BK2 + swc];
    if (kt + 2 < NK){
      const int kof = (kt+2)*BK2;
      gload16(gA0 + kof, &sA[b2][d0]); gload16(gA1 + kof, &sA[b2][d1]);
      gload16(gG0 + kof, &sG[b2][d0]); gload16(gG1 + kof, &sG[b2][d1]);
      gload16(gU0 + kof, &sU[b2][d0]); gload16(gU1 + kof, &sU[b2][d1]);
    }
    __builtin_amdgcn_s_setprio(1);
    #pragma unroll
    for (int ni=0;ni<4;ni++)
      #pragma unroll
      for (int mi=0;mi<4;mi++)
        accG[mi][ni] = __builtin_amdgcn_mfma_f32_16x16x32_bf16(a_[mi], bg_[ni], accG[mi][ni], 0,0,0);
    __builtin_amdgcn_s_setprio(0);
    // U frags (same wave, b0 not written this step -> no barrier needed), MFMA accU
    #pragma unroll
    for (int ni=0;ni<4;ni++)
      bu_[ni] = *(const short8v*)&sU[b0][(wn + ni*16 + lr)*BK2 + swc];
    __builtin_amdgcn_s_setprio(1);
    #pragma unroll
    for (int ni=0;ni<4;ni++)
      #pragma unroll
      for (int mi=0;mi<4;mi++)
        accU[mi][ni] = __builtin_amdgcn_mfma_f32_16x16x32_bf16(a_[mi], bu_[ni], accU[mi][ni], 0,0,0);
    __builtin_amdgcn_s_setprio(0);
    SCHED0;
    if (kt + 2 < NK)      WAITV6_BAR;   // kt+1 landed; kt+2 (6) in flight
    else if (kt + 1 < NK) WAITV0_BAR;
    int tb = b0; b0 = b1; b1 = b2; b2 = tb;
  }

  #pragma unroll
  for (int mi=0;mi<4;mi++){
    #pragma unroll
    for (int r=0;r<4;r++){
      const int row = row0 + wm + mi*16 + q*4 + r;
      ushort* hp = h1 + (size_t)row * I_DIM + n0 + wn + lr;
      #pragma unroll
      for (int ni=0;ni<4;ni++){
        float g = accG[mi][ni][r], u = accU[mi][ni][r];
        float sv = g / (1.f + __expf(-g));
        hp[ni*16] = (ushort)f2bf(sv * u);
      }
    }
  }
}

// ---------------- down GEMM: 128x128, 4 waves, 3-buf depth-2, ONE barrier/K-step ----------------
__global__ __launch_bounds__(256, 3) void down_kernel(
    const ushort* __restrict__ h1, const ushort* __restrict__ dwb,
    const int* __restrict__ tile_e, const int* __restrict__ tile_r,
    const int* __restrict__ hdr, ushort* __restrict__ ds_out)
{
  const int tile = blockIdx.y;
  if (tile >= hdr[0]) return;
  __shared__ short sA[3][BM*BK2];
  __shared__ short sB[3][BM*BK2];     // 48 KB -> 3 blocks/CU
  const int e = tile_e[tile];
  const int row0 = tile_r[tile];
  const int n0 = blockIdx.x * 128;
  const int tid = threadIdx.x, lane = tid & 63, wid = tid >> 6;

  const int srow = tid >> 2;
  const int scg  = ((tid & 3) ^ ((tid >> 3) & 3)) * 8;
  const int d0 = tid * 8, d1 = tid * 8 + 2048;
  const ushort* gA0 = h1  + (size_t)(row0 + srow)      * I_DIM + scg;
  const ushort* gA1 = h1  + (size_t)(row0 + srow + 64) * I_DIM + scg;
  const ushort* gB0 = dwb + ((size_t)e*H_DIM + n0 + srow)      * I_DIM + scg;
  const ushort* gB1 = dwb + ((size_t)e*H_DIM + n0 + srow + 64) * I_DIM + scg;

  const int wm = (wid >> 1) * 64, wn = (wid & 1) * 64;
  const int lr = lane & 15, q = lane >> 4;
  const int swc = (q ^ ((lr >> 1) & 3)) * 8;

  f32x4 acc[4][4] = {};

  gload16(gA0,       &sA[0][d0]); gload16(gA1,       &sA[0][d1]);
  gload16(gB0,       &sB[0][d0]); gload16(gB1,       &sB[0][d1]);
  gload16(gA0 + BK2, &sA[1][d0]); gload16(gA1 + BK2, &sA[1][d1]);
  gload16(gB0 + BK2, &sB[1][d0]); gload16(gB1 + BK2, &sB[1][d1]);
  WAITV4_BAR;

  const int NK = I_DIM / BK2;   // 64
  int b0 = 0, b1 = 1, b2 = 2;
  for (int kt = 0; kt < NK; ++kt){
    short8v a_[4], b_[4];
    #pragma unroll
    for (int mi=0;mi<4;mi++)
      a_[mi] = *(const short8v*)&sA[b0][(wm + mi*16 + lr)*BK2 + swc];
    #pragma unroll
    for (int ni=0;ni<4;ni++)
      b_[ni] = *(const short8v*)&sB[b0][(wn + ni*16 + lr)*BK2 + swc];
    if (kt + 2 < NK){
      const int kof = (kt+2)*BK2;
      gload16(gA0 + kof, &sA[b2][d0]); gload16(gA1 + kof, &sA[b2][d1]);
      gload16(gB0 + kof, &sB[b2][d0]); gload16(gB1 + kof, &sB[b2][d1]);
    }
    __builtin_amdgcn_s_setprio(1);
    #pragma unroll
    for (int ni=0;ni<4;ni++)
      #pragma unroll
      for (int mi=0;mi<4;mi++)
        acc[mi][ni] = __builtin_amdgcn_mfma_f32_16x16x32_bf16(a_[mi], b_[ni], acc[mi][ni], 0,0,0);
    __builtin_amdgcn_s_setprio(0);
    SCHED0;
    if (kt + 2 < NK)      WAITV4_BAR;
    else if (kt + 1 < NK) WAITV0_BAR;
    int tb = b0; b0 = b1; b1 = b2; b2 = tb;
  }

  #pragma unroll
  for (int mi=0;mi<4;mi++){
    #pragma unroll
    for (int r=0;r<4;r++){
      const int prow = row0 + wm + mi*16 + q*4 + r;
      ushort* op = ds_out + (size_t)prow * H_DIM + n0 + wn + lr;
      #pragma unroll
      for (int ni=0;ni<4;ni++)
        op[ni*16] = (ushort)f2bf(acc[mi][ni][r]);
    }
  }
}

// ---------------- combine: out[t] = w1*ds[s1] + w2*ds[s2] ----------------
__global__ __launch_bounds__(256) void combine_kernel(const ushort* __restrict__ ds_out,
    const int* __restrict__ slot_idx, const float* __restrict__ s_wt,
    float* __restrict__ out){
  const int t   = blockIdx.x * 2 + (threadIdx.x >> 7);
  const int col = (threadIdx.x & 127) * 8;
  const int s1 = slot_idx[2*t], s2 = slot_idx[2*t+1];
  const float w1 = s_wt[s1], w2 = s_wt[s2];
  const u32x4 a = *(const u32x4*)(ds_out + (size_t)s1 * H_DIM + col);
  const u32x4 b = *(const u32x4*)(ds_out + (size_t)s2 * H_DIM + col);
  float* op = out + (size_t)t * H_DIM + col;
  f32x4 o0, o1;
  o0.x = w1*bflo(a.x) + w2*bflo(b.x);
  o0.y = w1*bfhi(a.x) + w2*bfhi(b.x);
  o0.z = w1*bflo(a.y) + w2*bflo(b.y);
  o0.w = w1*bfhi(a.y) + w2*bfhi(b.y);
  o1.x = w1*bflo(a.z) + w2*bflo(b.z);
  o1.y = w1*bfhi(a.z) + w2*bfhi(b.z);
  o1.z = w1*bflo(a.w) + w2*bflo(b.w);
  o1.w = w1*bfhi(a.w) + w2*bfhi(b.w);
  *(f32x4*)op       = o0;
  *(f32x4*)(op + 4) = o1;
}

extern "C" void kernel_launch(void* const* d_in, const int* in_sizes, int n_in,
                              void* d_out, int out_size, void* d_ws, size_t ws_size,
                              hipStream_t stream){
  const float* x   = (const float*)d_in[0];
  const float* rw  = (const float*)d_in[1];
  const float* gw  = (const float*)d_in[2];
  const float* uw  = (const float*)d_in[3];
  const float* dwn = (const float*)d_in[4];
  float* out = (float*)d_out;

  char* w = (char*)d_ws;
  int*   hdr        = (int*)(w + 0);
  int*   tile_e     = (int*)(w + 256);
  int*   tile_r     = (int*)(w + 1280);
  int*   block_hist = (int*)(w + 2304);
  int*   block_base = (int*)(w + 3328);
  int*   s_tok      = (int*)(w + 8192);
  float* s_wt       = (float*)(w + 8192 + PADMAX*4);
  int*   pe         = (int*)(w + 8192 + PADMAX*8);
  float* pw         = (float*)(w + 8192 + PADMAX*8 + T_TOK*2*4);
  int*   slot_idx   = (int*)(w + 8192 + PADMAX*8 + T_TOK*2*8);
  float* avg_part   = (float*)(w + 8192 + PADMAX*8 + T_TOK*2*12);
  ushort* xb        = (ushort*)(w + 409600);
  ushort* h1        = (ushort*)(w + 409600 + (size_t)T_TOK*H_DIM*2);
  ushort* gwb       = (ushort*)(w + 409600 + (size_t)T_TOK*H_DIM*2 + (size_t)PADMAX*I_DIM*2);
  ushort* uwb       = gwb + (size_t)E_NUM*I_DIM*H_DIM;
  ushort* dwb       = uwb + (size_t)E_NUM*I_DIM*H_DIM;
  ushort* ds_out    = gwb;   // overlay: gwb/uwb dead after gateup

  size_t need = 409600 + (size_t)T_TOK*H_DIM*2 + (size_t)PADMAX*I_DIM*2
              + 3ull * E_NUM*I_DIM*H_DIM * 2;
  if (ws_size < need){
    fprintf(stderr, "kernel_launch: ws too small (%zu < %zu)\n", ws_size, need);
    return;
  }

  convert4_kernel<<<NXB + 3*NWB, 256, 0, stream>>>(x, gw, uw, dwn, xb, gwb, uwb, dwb);
  router_kernel<<<T_TOK/4, 256, 0, stream>>>(x, rw, out, pe, pw, avg_part);
  hist_kernel<<<HB, 256, 0, stream>>>(pe, block_hist);
  offsets_kernel<<<1, 256, 0, stream>>>(block_hist, avg_part, block_base,
                                        tile_e, tile_r, hdr, s_tok, s_wt, out);
  scatter_kernel<<<HB, 256, 0, stream>>>(pe, pw, block_base, s_tok, s_wt, slot_idx);
  gateup_kernel<<<dim3(I_DIM/128, MAX_TILES), 256, 0, stream>>>(xb, gwb, uwb, s_tok, tile_e, tile_r, hdr, h1);
  down_kernel<<<dim3(H_DIM/128, MAX_TILES), 256, 0, stream>>>(h1, dwb, tile_e, tile_r, hdr, ds_out);
  combine_kernel<<<T_TOK/2, 256, 0, stream>>>(ds_out, slot_idx, s_wt, out);
}

// Round 17
// 361.776 us; speedup vs baseline: 1.0499x; 1.0499x over previous
//
#include <hip/hip_runtime.h>
#include <hip/hip_bf16.h>
#include <cstdio>
#include <cstdint>

#define T_TOK   8192
#define H_DIM   1024
#define I_DIM   2048
#define E_NUM   8
#define BM      128
#define BK2     32
#define PADMAX  17408         // T*K + E*BM
#define MAX_TILES 136         // T*K/BM + E
#define HB      32            // histogram/scatter blocks
#define PAIRS_PER_HB (T_TOK*2/HB)   // 512

#define OUT_FRAC  8388608
#define OUT_AVG   8388616
#define OUT_LOG   8388624
#define OUT_PROB  8454160

typedef short short8v __attribute__((ext_vector_type(8)));
typedef float f32x4   __attribute__((ext_vector_type(4)));
typedef unsigned int u32x4 __attribute__((ext_vector_type(4)));

#define AS1 __attribute__((address_space(1)))
#define AS3 __attribute__((address_space(3)))
__device__ __forceinline__ void gload16(const void* g, void* l){
  __builtin_amdgcn_global_load_lds((const AS1 void*)g, (AS3 void*)l, 16, 0, 0);
}

#define WAITV6_BAR asm volatile("s_waitcnt vmcnt(6)\n\ts_barrier" ::: "memory")
#define WAITV4_BAR asm volatile("s_waitcnt vmcnt(4)\n\ts_barrier" ::: "memory")
#define WAITV0_BAR asm volatile("s_waitcnt vmcnt(0)\n\ts_barrier" ::: "memory")
#define SBAR  __builtin_amdgcn_s_barrier()
#define SCHED0 __builtin_amdgcn_sched_barrier(0)

__device__ __forceinline__ uint32_t f2bf(float f){
  union { float f; uint32_t u; } v; v.f = f;
  return (v.u + 0x7FFFu + ((v.u >> 16) & 1u)) >> 16;   // RNE
}
__device__ __forceinline__ uint32_t pack2(float a, float b){
  return f2bf(a) | (f2bf(b) << 16);
}
__device__ __forceinline__ float bflo(uint32_t u){ union{uint32_t u;float f;}v; v.u = u<<16; return v.f; }
__device__ __forceinline__ float bfhi(uint32_t u){ union{uint32_t u;float f;}v; v.u = u & 0xFFFF0000u; return v.f; }

// ---------------- fused fp32 -> bf16 weight convert (gw, uw, dw) ----------------
#define NWB  (E_NUM*I_DIM*H_DIM/2048)    // 8192
__global__ __launch_bounds__(256) void convert3_kernel(
    const float* __restrict__ gw, const float* __restrict__ uw,
    const float* __restrict__ dw,
    ushort* __restrict__ gwb, ushort* __restrict__ uwb, ushort* __restrict__ dwb){
  const int b = blockIdx.x;
  const float* src; ushort* dst; size_t base;
  if (b < NWB)        { src = gw; dst = gwb; base = (size_t)b * 2048; }
  else if (b < 2*NWB) { src = uw; dst = uwb; base = (size_t)(b-NWB) * 2048; }
  else                { src = dw; dst = dwb; base = (size_t)(b-2*NWB) * 2048; }
  size_t i = base + (size_t)threadIdx.x * 8;
  f32x4 f0 = *(const f32x4*)(src + i);
  f32x4 f1 = *(const f32x4*)(src + i + 4);
  u32x4 o;
  o.x = pack2(f0.x, f0.y); o.y = pack2(f0.z, f0.w);
  o.z = pack2(f1.x, f1.y); o.w = pack2(f1.z, f1.w);
  *(u32x4*)(dst + i) = o;
}

// ---------------- router: logits/softmax/top2 + x->bf16 byproduct; NO global atomics ----------------
__global__ __launch_bounds__(256) void router_kernel(const float* __restrict__ x,
    const float* __restrict__ rw, float* __restrict__ out,
    int* __restrict__ pe, float* __restrict__ pw, float* __restrict__ avg_part,
    ushort* __restrict__ xb){
  __shared__ float s_rw[E_NUM * H_DIM];
  __shared__ float s_avg[E_NUM];
  const int tid = threadIdx.x;
  for (int i = tid; i < E_NUM*H_DIM/4; i += 256)
    ((float4*)s_rw)[i] = ((const float4*)rw)[i];
  if (tid < E_NUM) s_avg[tid] = 0.f;
  __syncthreads();
  const int lane = tid & 63;
  const int t = blockIdx.x * 4 + (tid >> 6);
  float acc[E_NUM];
  #pragma unroll
  for (int e=0;e<E_NUM;e++) acc[e] = 0.f;
  const float* xr = x + (size_t)t * H_DIM;
  ushort* xbr = xb + (size_t)t * H_DIM;
  for (int c=0;c<H_DIM/64;c++){
    float xv = xr[c*64 + lane];
    xbr[c*64 + lane] = (ushort)f2bf(xv);          // fused x->bf16 store
    #pragma unroll
    for (int e=0;e<E_NUM;e++) acc[e] += xv * s_rw[e*H_DIM + c*64 + lane];
  }
  #pragma unroll
  for (int e=0;e<E_NUM;e++){
    #pragma unroll
    for (int off=32; off; off>>=1) acc[e] += __shfl_xor(acc[e], off);
  }
  if (lane == 0){
    float m = acc[0];
    #pragma unroll
    for (int e=1;e<E_NUM;e++) m = fmaxf(m, acc[e]);
    float p[E_NUM]; float s = 0.f;
    #pragma unroll
    for (int e=0;e<E_NUM;e++){ p[e] = __expf(acc[e]-m); s += p[e]; }
    float inv = 1.f/s;
    #pragma unroll
    for (int e=0;e<E_NUM;e++) p[e] *= inv;
    float* lg = out + OUT_LOG  + (size_t)t*E_NUM;
    float* pr = out + OUT_PROB + (size_t)t*E_NUM;
    #pragma unroll
    for (int e=0;e<E_NUM;e++){ lg[e] = acc[e]; pr[e] = p[e]; }
    #pragma unroll
    for (int e=0;e<E_NUM;e++) atomicAdd(&s_avg[e], p[e]);   // LDS atomic (cheap)
    int e1 = 0; float p1 = p[0];
    #pragma unroll
    for (int e=1;e<E_NUM;e++) if (p[e] > p1){ p1 = p[e]; e1 = e; }
    int e2 = -1; float p2 = -1.f;
    #pragma unroll
    for (int e=0;e<E_NUM;e++) if (e != e1 && p[e] > p2){ p2 = p[e]; e2 = e; }
    float rs = 1.f/(p1+p2);
    pe[2*t]   = e1; pw[2*t]   = p1*rs;
    pe[2*t+1] = e2; pw[2*t+1] = p2*rs;
  }
  __syncthreads();
  if (tid < E_NUM) avg_part[blockIdx.x*E_NUM + tid] = s_avg[tid];
}

// ---------------- per-block expert histogram (LDS atomics only) ----------------
__global__ __launch_bounds__(256) void hist_kernel(const int* __restrict__ pe,
                                                   int* __restrict__ block_hist){
  __shared__ int h[E_NUM];
  if (threadIdx.x < E_NUM) h[threadIdx.x] = 0;
  __syncthreads();
  const int base = blockIdx.x * PAIRS_PER_HB;
  for (int i = threadIdx.x; i < PAIRS_PER_HB; i += 256)
    atomicAdd(&h[pe[base + i]], 1);
  __syncthreads();
  if (threadIdx.x < E_NUM) block_hist[blockIdx.x*E_NUM + threadIdx.x] = h[threadIdx.x];
}

// ---------------- offsets: counts/frac/avg + tile table + per-block bases + zero pads ----------------
__global__ __launch_bounds__(256) void offsets_kernel(const int* __restrict__ block_hist,
    const float* __restrict__ avg_part, int* __restrict__ block_base,
    int* __restrict__ tile_e, int* __restrict__ tile_r, int* __restrict__ hdr,
    int* __restrict__ s_tok, float* __restrict__ s_wt, float* __restrict__ out){
  __shared__ int counts[E_NUM];
  __shared__ float ap[256];
  const int tid = threadIdx.x;
  {
    const int e = tid & 7, chunk = tid >> 3;
    float s = 0.f;
    #pragma unroll 8
    for (int i = 0; i < 64; ++i)
      s += avg_part[(chunk*64 + i)*E_NUM + e];
    ap[tid] = s;
  }
  if (tid < E_NUM){
    int c = 0;
    #pragma unroll
    for (int b = 0; b < HB; ++b) c += block_hist[b*E_NUM + tid];
    counts[tid] = c;
  }
  __syncthreads();
  if (tid < E_NUM){
    float tot = 0.f;
    #pragma unroll
    for (int c = 0; c < 32; ++c) tot += ap[c*8 + tid];
    out[OUT_AVG  + tid] = tot * (1.f/8192.f);
    out[OUT_FRAC + tid] = (float)counts[tid] * (1.f/16384.f);
  }
  if (tid == 0){
    int base = 0, tt = 0;
    for (int e=0;e<E_NUM;e++){
      int run = base;
      for (int b=0;b<HB;b++){
        block_base[b*E_NUM + e] = run;
        run += block_hist[b*E_NUM + e];
      }
      int nt = (counts[e] + BM - 1) / BM;
      for (int i=0;i<nt;i++){ tile_e[tt] = e; tile_r[tt] = base + i*BM; tt++; }
      base += nt * BM;
    }
    hdr[0] = tt; hdr[1] = base;
  }
  for (int i = tid; i < PADMAX; i += blockDim.x){
    s_tok[i] = 0; s_wt[i] = 0.f;
  }
}

// ---------------- scatter: local rank via LDS atomics + precomputed block base ----------------
__global__ __launch_bounds__(256) void scatter_kernel(const int* __restrict__ pe,
    const float* __restrict__ pw, const int* __restrict__ block_base,
    int* __restrict__ s_tok, float* __restrict__ s_wt, int* __restrict__ slot_idx){
  __shared__ int h[E_NUM];
  if (threadIdx.x < E_NUM) h[threadIdx.x] = 0;
  __syncthreads();
  const int base = blockIdx.x * PAIRS_PER_HB;
  for (int i = threadIdx.x; i < PAIRS_PER_HB; i += 256){
    const int pi = base + i;
    const int e = pe[pi];
    const int r = atomicAdd(&h[e], 1);
    const int idx = block_base[blockIdx.x*E_NUM + e] + r;
    s_tok[idx] = pi >> 1;
    s_wt[idx]  = pw[pi];
    slot_idx[pi] = idx;
  }
}

// ---------------- gate+up GEMM: 128x128 tile, 4 waves, 3-buf, 2 fine phases (R14) ----------------
__global__ __launch_bounds__(256, 2) void gateup_kernel(
    const ushort* __restrict__ xb, const ushort* __restrict__ gwb,
    const ushort* __restrict__ uwb, const int* __restrict__ s_tok,
    const int* __restrict__ tile_e, const int* __restrict__ tile_r,
    const int* __restrict__ hdr, ushort* __restrict__ h1)
{
  const int tile = blockIdx.y;
  if (tile >= hdr[0]) return;
  __shared__ short sA[3][BM*BK2];
  __shared__ short sG[3][BM*BK2];
  __shared__ short sU[3][BM*BK2];     // 72 KB -> 2 blocks/CU (reg-limited anyway)
  const int e = tile_e[tile];
  const int row0 = tile_r[tile];
  const int n0 = blockIdx.x * 128;
  const int tid = threadIdx.x, lane = tid & 63, wid = tid >> 6;

  const int srow = tid >> 2;
  const int scg  = ((tid & 3) ^ ((tid >> 3) & 3)) * 8;
  const int d0 = tid * 8, d1 = tid * 8 + 2048;
  const ushort* gA0 = xb  + (size_t)s_tok[row0 + srow]      * H_DIM + scg;
  const ushort* gA1 = xb  + (size_t)s_tok[row0 + srow + 64] * H_DIM + scg;
  const ushort* gG0 = gwb + ((size_t)e*I_DIM + n0 + srow)      * H_DIM + scg;
  const ushort* gG1 = gwb + ((size_t)e*I_DIM + n0 + srow + 64) * H_DIM + scg;
  const ushort* gU0 = uwb + ((size_t)e*I_DIM + n0 + srow)      * H_DIM + scg;
  const ushort* gU1 = uwb + ((size_t)e*I_DIM + n0 + srow + 64) * H_DIM + scg;

  const int wm = (wid >> 1) * 64, wn = (wid & 1) * 64;
  const int lr = lane & 15, q = lane >> 4;
  const int swc = (q ^ ((lr >> 1) & 3)) * 8;

  f32x4 accG[4][4] = {};
  f32x4 accU[4][4] = {};

  gload16(gA0,       &sA[0][d0]); gload16(gA1,       &sA[0][d1]);
  gload16(gG0,       &sG[0][d0]); gload16(gG1,       &sG[0][d1]);
  gload16(gU0,       &sU[0][d0]); gload16(gU1,       &sU[0][d1]);
  gload16(gA0 + BK2, &sA[1][d0]); gload16(gA1 + BK2, &sA[1][d1]);
  gload16(gG0 + BK2, &sG[1][d0]); gload16(gG1 + BK2, &sG[1][d1]);
  gload16(gU0 + BK2, &sU[1][d0]); gload16(gU1 + BK2, &sU[1][d1]);
  WAITV6_BAR;

  const int NK = H_DIM / BK2;   // 32
  int b0 = 0, b1 = 1, b2 = 2;
  for (int kt = 0; kt < NK; ++kt){
    short8v a_[4], bg_[4], bu_[4];
    #pragma unroll
    for (int mi=0;mi<4;mi++)
      a_[mi] = *(const short8v*)&sA[b0][(wm + mi*16 + lr)*BK2 + swc];
    #pragma unroll
    for (int ni=0;ni<4;ni++)
      bg_[ni] = *(const short8v*)&sG[b0][(wn + ni*16 + lr)*BK2 + swc];
    if (kt + 2 < NK){
      const int kof = (kt+2)*BK2;
      gload16(gA0 + kof, &sA[b2][d0]); gload16(gA1 + kof, &sA[b2][d1]);
      gload16(gG0 + kof, &sG[b2][d0]); gload16(gG1 + kof, &sG[b2][d1]);
    }
    SCHED0; SBAR; SCHED0;
    __builtin_amdgcn_s_setprio(1);
    #pragma unroll
    for (int ni=0;ni<4;ni++)
      #pragma unroll
      for (int mi=0;mi<4;mi++)
        accG[mi][ni] = __builtin_amdgcn_mfma_f32_16x16x32_bf16(a_[mi], bg_[ni], accG[mi][ni], 0,0,0);
    __builtin_amdgcn_s_setprio(0);
    SCHED0; SBAR;
    #pragma unroll
    for (int ni=0;ni<4;ni++)
      bu_[ni] = *(const short8v*)&sU[b0][(wn + ni*16 + lr)*BK2 + swc];
    if (kt + 2 < NK){
      const int kof = (kt+2)*BK2;
      gload16(gU0 + kof, &sU[b2][d0]); gload16(gU1 + kof, &sU[b2][d1]);
    }
    SCHED0; SBAR; SCHED0;
    __builtin_amdgcn_s_setprio(1);
    #pragma unroll
    for (int ni=0;ni<4;ni++)
      #pragma unroll
      for (int mi=0;mi<4;mi++)
        accU[mi][ni] = __builtin_amdgcn_mfma_f32_16x16x32_bf16(a_[mi], bu_[ni], accU[mi][ni], 0,0,0);
    __builtin_amdgcn_s_setprio(0);
    SCHED0;
    if (kt + 2 < NK)      WAITV6_BAR;
    else if (kt + 1 < NK) WAITV0_BAR;
    int tb = b0; b0 = b1; b1 = b2; b2 = tb;
  }

  #pragma unroll
  for (int mi=0;mi<4;mi++){
    #pragma unroll
    for (int r=0;r<4;r++){
      const int row = row0 + wm + mi*16 + q*4 + r;
      ushort* hp = h1 + (size_t)row * I_DIM + n0 + wn + lr;
      #pragma unroll
      for (int ni=0;ni<4;ni++){
        float g = accG[mi][ni][r], u = accU[mi][ni][r];
        float sv = g / (1.f + __expf(-g));
        hp[ni*16] = (ushort)f2bf(sv * u);
      }
    }
  }
}

// ---------------- down GEMM: 128x128 tile, 4 waves, 3-buf, 2 fine phases (R14) ----------------
__global__ __launch_bounds__(256, 3) void down_kernel(
    const ushort* __restrict__ h1, const ushort* __restrict__ dwb,
    const int* __restrict__ tile_e, const int* __restrict__ tile_r,
    const int* __restrict__ hdr, ushort* __restrict__ ds_out)
{
  const int tile = blockIdx.y;
  if (tile >= hdr[0]) return;
  __shared__ short sA[3][BM*BK2];
  __shared__ short sB[3][BM*BK2];     // 48 KB -> 3 blocks/CU
  const int e = tile_e[tile];
  const int row0 = tile_r[tile];
  const int n0 = blockIdx.x * 128;
  const int tid = threadIdx.x, lane = tid & 63, wid = tid >> 6;

  const int srow = tid >> 2;
  const int scg  = ((tid & 3) ^ ((tid >> 3) & 3)) * 8;
  const int d0 = tid * 8, d1 = tid * 8 + 2048;
  const ushort* gA0 = h1  + (size_t)(row0 + srow)      * I_DIM + scg;
  const ushort* gA1 = h1  + (size_t)(row0 + srow + 64) * I_DIM + scg;
  const ushort* gB0 = dwb + ((size_t)e*H_DIM + n0 + srow)      * I_DIM + scg;
  const ushort* gB1 = dwb + ((size_t)e*H_DIM + n0 + srow + 64) * I_DIM + scg;

  const int wm = (wid >> 1) * 64, wn = (wid & 1) * 64;
  const int lr = lane & 15, q = lane >> 4;
  const int swc = (q ^ ((lr >> 1) & 3)) * 8;

  f32x4 acc[4][4] = {};

  gload16(gA0,       &sA[0][d0]); gload16(gA1,       &sA[0][d1]);
  gload16(gB0,       &sB[0][d0]); gload16(gB1,       &sB[0][d1]);
  gload16(gA0 + BK2, &sA[1][d0]); gload16(gA1 + BK2, &sA[1][d1]);
  gload16(gB0 + BK2, &sB[1][d0]); gload16(gB1 + BK2, &sB[1][d1]);
  WAITV4_BAR;

  const int NK = I_DIM / BK2;   // 64
  int b0 = 0, b1 = 1, b2 = 2;
  for (int kt = 0; kt < NK; ++kt){
    short8v a_[4], b_[4];
    #pragma unroll
    for (int mi=0;mi<4;mi++)
      a_[mi] = *(const short8v*)&sA[b0][(wm + mi*16 + lr)*BK2 + swc];
    #pragma unroll
    for (int ni=0;ni<2;ni++)
      b_[ni] = *(const short8v*)&sB[b0][(wn + ni*16 + lr)*BK2 + swc];
    if (kt + 2 < NK){
      const int kof = (kt+2)*BK2;
      gload16(gA0 + kof, &sA[b2][d0]); gload16(gA1 + kof, &sA[b2][d1]);
    }
    SCHED0; SBAR; SCHED0;
    __builtin_amdgcn_s_setprio(1);
    #pragma unroll
    for (int ni=0;ni<2;ni++)
      #pragma unroll
      for (int mi=0;mi<4;mi++)
        acc[mi][ni] = __builtin_amdgcn_mfma_f32_16x16x32_bf16(a_[mi], b_[ni], acc[mi][ni], 0,0,0);
    __builtin_amdgcn_s_setprio(0);
    SCHED0; SBAR;
    #pragma unroll
    for (int ni=2;ni<4;ni++)
      b_[ni] = *(const short8v*)&sB[b0][(wn + ni*16 + lr)*BK2 + swc];
    if (kt + 2 < NK){
      const int kof = (kt+2)*BK2;
      gload16(gB0 + kof, &sB[b2][d0]); gload16(gB1 + kof, &sB[b2][d1]);
    }
    SCHED0; SBAR; SCHED0;
    __builtin_amdgcn_s_setprio(1);
    #pragma unroll
    for (int ni=2;ni<4;ni++)
      #pragma unroll
      for (int mi=0;mi<4;mi++)
        acc[mi][ni] = __builtin_amdgcn_mfma_f32_16x16x32_bf16(a_[mi], b_[ni], acc[mi][ni], 0,0,0);
    __builtin_amdgcn_s_setprio(0);
    SCHED0;
    if (kt + 2 < NK)      WAITV4_BAR;
    else if (kt + 1 < NK) WAITV0_BAR;
    int tb = b0; b0 = b1; b1 = b2; b2 = tb;
  }

  #pragma unroll
  for (int mi=0;mi<4;mi++){
    #pragma unroll
    for (int r=0;r<4;r++){
      const int prow = row0 + wm + mi*16 + q*4 + r;
      ushort* op = ds_out + (size_t)prow * H_DIM + n0 + wn + lr;
      #pragma unroll
      for (int ni=0;ni<4;ni++)
        op[ni*16] = (ushort)f2bf(acc[mi][ni][r]);
    }
  }
}

// ---------------- combine: out[t] = w1*ds[s1] + w2*ds[s2] ----------------
__global__ __launch_bounds__(256) void combine_kernel(const ushort* __restrict__ ds_out,
    const int* __restrict__ slot_idx, const float* __restrict__ s_wt,
    float* __restrict__ out){
  const int t   = blockIdx.x * 2 + (threadIdx.x >> 7);
  const int col = (threadIdx.x & 127) * 8;
  const int s1 = slot_idx[2*t], s2 = slot_idx[2*t+1];
  const float w1 = s_wt[s1], w2 = s_wt[s2];
  const u32x4 a = *(const u32x4*)(ds_out + (size_t)s1 * H_DIM + col);
  const u32x4 b = *(const u32x4*)(ds_out + (size_t)s2 * H_DIM + col);
  float* op = out + (size_t)t * H_DIM + col;
  f32x4 o0, o1;
  o0.x = w1*bflo(a.x) + w2*bflo(b.x);
  o0.y = w1*bfhi(a.x) + w2*bfhi(b.x);
  o0.z = w1*bflo(a.y) + w2*bflo(b.y);
  o0.w = w1*bfhi(a.y) + w2*bfhi(b.y);
  o1.x = w1*bflo(a.z) + w2*bflo(b.z);
  o1.y = w1*bfhi(a.z) + w2*bfhi(b.z);
  o1.z = w1*bflo(a.w) + w2*bflo(b.w);
  o1.w = w1*bfhi(a.w) + w2*bfhi(b.w);
  *(f32x4*)op       = o0;
  *(f32x4*)(op + 4) = o1;
}

extern "C" void kernel_launch(void* const* d_in, const int* in_sizes, int n_in,
                              void* d_out, int out_size, void* d_ws, size_t ws_size,
                              hipStream_t stream){
  const float* x   = (const float*)d_in[0];
  const float* rw  = (const float*)d_in[1];
  const float* gw  = (const float*)d_in[2];
  const float* uw  = (const float*)d_in[3];
  const float* dwn = (const float*)d_in[4];
  float* out = (float*)d_out;

  char* w = (char*)d_ws;
  int*   hdr        = (int*)(w + 0);
  int*   tile_e     = (int*)(w + 256);
  int*   tile_r     = (int*)(w + 1280);
  int*   block_hist = (int*)(w + 2304);
  int*   block_base = (int*)(w + 3328);
  int*   s_tok      = (int*)(w + 8192);
  float* s_wt       = (float*)(w + 8192 + PADMAX*4);
  int*   pe         = (int*)(w + 8192 + PADMAX*8);
  float* pw         = (float*)(w + 8192 + PADMAX*8 + T_TOK*2*4);
  int*   slot_idx   = (int*)(w + 8192 + PADMAX*8 + T_TOK*2*8);
  float* avg_part   = (float*)(w + 8192 + PADMAX*8 + T_TOK*2*12);
  ushort* xb        = (ushort*)(w + 409600);
  ushort* h1        = (ushort*)(w + 409600 + (size_t)T_TOK*H_DIM*2);
  ushort* gwb       = (ushort*)(w + 409600 + (size_t)T_TOK*H_DIM*2 + (size_t)PADMAX*I_DIM*2);
  ushort* uwb       = gwb + (size_t)E_NUM*I_DIM*H_DIM;
  ushort* dwb       = uwb + (size_t)E_NUM*I_DIM*H_DIM;
  ushort* ds_out    = gwb;   // overlay: gwb/uwb dead after gateup

  size_t need = 409600 + (size_t)T_TOK*H_DIM*2 + (size_t)PADMAX*I_DIM*2
              + 3ull * E_NUM*I_DIM*H_DIM * 2;
  if (ws_size < need){
    fprintf(stderr, "kernel_launch: ws too small (%zu < %zu)\n", ws_size, need);
    return;
  }

  convert3_kernel<<<3*NWB, 256, 0, stream>>>(gw, uw, dwn, gwb, uwb, dwb);
  router_kernel<<<T_TOK/4, 256, 0, stream>>>(x, rw, out, pe, pw, avg_part, xb);
  hist_kernel<<<HB, 256, 0, stream>>>(pe, block_hist);
  offsets_kernel<<<1, 256, 0, stream>>>(block_hist, avg_part, block_base,
                                        tile_e, tile_r, hdr, s_tok, s_wt, out);
  scatter_kernel<<<HB, 256, 0, stream>>>(pe, pw, block_base, s_tok, s_wt, slot_idx);
  gateup_kernel<<<dim3(I_DIM/128, MAX_TILES), 256, 0, stream>>>(xb, gwb, uwb, s_tok, tile_e, tile_r, hdr, h1);
  down_kernel<<<dim3(H_DIM/128, MAX_TILES), 256, 0, stream>>>(h1, dwb, tile_e, tile_r, hdr, ds_out);
  combine_kernel<<<T_TOK/2, 256, 0, stream>>>(ds_out, slot_idx, s_wt, out);
}